// Round 1
// baseline (485.983 us; speedup 1.0000x reference)
//
#include <hip/hip_runtime.h>
#include <math.h>

#define N_NODES 50000
#define N_EDGES 800000
#define D0 64
#define D1 128
#define D2 40

// ---------------- CSR build ----------------

__global__ void count_deg_kernel(const int* __restrict__ dst, int* __restrict__ deg, int E) {
    int e = blockIdx.x * blockDim.x + threadIdx.x;
    if (e < E) atomicAdd(&deg[dst[e]], 1);
}

// single-block exclusive scan of deg[N] -> rowptr[N+1], also initializes cursor = rowptr
__global__ void scan_kernel(const int* __restrict__ deg, int* __restrict__ rowptr,
                            int* __restrict__ cursor, int N) {
    __shared__ int sd[1024];
    int t = threadIdx.x;
    int CH = (N + 1023) >> 10;   // elements per thread
    int base = t * CH;
    int sum = 0;
    for (int i = 0; i < CH; ++i) {
        int idx = base + i;
        if (idx < N) sum += deg[idx];
    }
    sd[t] = sum;
    __syncthreads();
    // Hillis-Steele inclusive scan over 1024 thread sums
    for (int off = 1; off < 1024; off <<= 1) {
        int v = 0;
        if (t >= off) v = sd[t - off];
        __syncthreads();
        sd[t] += v;
        __syncthreads();
    }
    int run = sd[t] - sum;  // exclusive prefix for this thread's chunk
    for (int i = 0; i < CH; ++i) {
        int idx = base + i;
        if (idx < N) {
            rowptr[idx] = run;
            cursor[idx] = run;
            run += deg[idx];
        }
    }
    if (t == 1023) rowptr[N] = sd[1023];
}

__global__ void fill_csr_kernel(const int* __restrict__ src, const int* __restrict__ dst,
                                int* __restrict__ cursor, int* __restrict__ csr, int E) {
    int e = blockIdx.x * blockDim.x + threadIdx.x;
    if (e < E) {
        int p = atomicAdd(&cursor[dst[e]], 1);
        csr[p] = src[e];
    }
}

// ---------------- aggregation (mean over incoming edges) ----------------

// one wave per node, D0=64: lane = feature index
__global__ void agg1_kernel(const float* __restrict__ x, const int* __restrict__ rowptr,
                            const int* __restrict__ csr, float* __restrict__ agg, int N) {
    int wid = (blockIdx.x * blockDim.x + threadIdx.x) >> 6;
    int lane = threadIdx.x & 63;
    if (wid >= N) return;
    int beg = rowptr[wid], end = rowptr[wid + 1];
    float acc = 0.f;
    for (int base = beg; base < end; base += 64) {
        int cnt = min(64, end - base);
        int sl = (base + lane < end) ? csr[base + lane] : 0;
        for (int i = 0; i < cnt; ++i) {
            int s = __shfl(sl, i);
            acc += x[(size_t)s * D0 + lane];
        }
    }
    float d = (float)max(end - beg, 1);
    agg[(size_t)wid * D0 + lane] = acc / d;
}

// one wave per node, D1=128: lane handles float2 at column 2*lane
__global__ void agg2_kernel(const float* __restrict__ h, const int* __restrict__ rowptr,
                            const int* __restrict__ csr, float* __restrict__ agg, int N) {
    int wid = (blockIdx.x * blockDim.x + threadIdx.x) >> 6;
    int lane = threadIdx.x & 63;
    if (wid >= N) return;
    int beg = rowptr[wid], end = rowptr[wid + 1];
    float ax = 0.f, ay = 0.f;
    for (int base = beg; base < end; base += 64) {
        int cnt = min(64, end - base);
        int sl = (base + lane < end) ? csr[base + lane] : 0;
        for (int i = 0; i < cnt; ++i) {
            int s = __shfl(sl, i);
            float2 v = ((const float2*)(h + (size_t)s * D1))[lane];
            ax += v.x;
            ay += v.y;
        }
    }
    float inv = 1.f / (float)max(end - beg, 1);
    float2 o; o.x = ax * inv; o.y = ay * inv;
    ((float2*)(agg + (size_t)wid * D1))[lane] = o;
}

// ---------------- GEMMs (fp32 vector ALU; no f32 MFMA on CDNA4) ----------------

#define MAC8(vs, wp) {                                              \
    float4 w0 = *(const float4*)(wp);                               \
    float4 w1 = *(const float4*)((wp) + 4);                         \
    acc[0] += (vs) * w0.x; acc[1] += (vs) * w0.y;                   \
    acc[2] += (vs) * w0.z; acc[3] += (vs) * w0.w;                   \
    acc[4] += (vs) * w1.x; acc[5] += (vs) * w1.y;                   \
    acc[6] += (vs) * w1.z; acc[7] += (vs) * w1.w; }

// h = relu(agg1 @ W1l + b1 + x @ W1r); LDS holds Wc[128][128]:
// rows 0..63 = W1r (multiplies x), rows 64..127 = W1l (multiplies agg1)
__global__ __launch_bounds__(256) void gemm1_kernel(
        const float* __restrict__ x, const float* __restrict__ agg,
        const float* __restrict__ W1l, const float* __restrict__ W1r,
        const float* __restrict__ b1, float* __restrict__ h, int N) {
    __shared__ float Wc[128 * 128];
    int t = threadIdx.x;
    {
        float4* wd = (float4*)Wc;
        const float4* wr = (const float4*)W1r;
        const float4* wl = (const float4*)W1l;
        for (int i = t; i < 4096; i += 256)
            wd[i] = (i < 2048) ? wr[i] : wl[i - 2048];
    }
    __syncthreads();
    int jc = t & 15, j0 = jc * 8;
    int rlocal = t >> 4;           // 16 rows per tile
    float4 bb0 = ((const float4*)(b1 + j0))[0];
    float4 bb1 = ((const float4*)(b1 + j0))[1];
    int ntiles = (N + 15) >> 4;
    for (int tile = blockIdx.x; tile < ntiles; tile += gridDim.x) {
        int r = tile * 16 + rlocal;
        if (r >= N) continue;
        float acc[8] = {bb0.x, bb0.y, bb0.z, bb0.w, bb1.x, bb1.y, bb1.z, bb1.w};
        const float4* xr = (const float4*)(x + (size_t)r * D0);
#pragma unroll
        for (int k4 = 0; k4 < 16; ++k4) {
            float4 v = xr[k4];
            const float* wp = &Wc[(k4 * 4) * 128 + j0];
            MAC8(v.x, wp); MAC8(v.y, wp + 128); MAC8(v.z, wp + 256); MAC8(v.w, wp + 384);
        }
        const float4* ar = (const float4*)(agg + (size_t)r * D0);
#pragma unroll
        for (int k4 = 0; k4 < 16; ++k4) {
            float4 v = ar[k4];
            const float* wp = &Wc[(64 + k4 * 4) * 128 + j0];
            MAC8(v.x, wp); MAC8(v.y, wp + 128); MAC8(v.z, wp + 256); MAC8(v.w, wp + 384);
        }
        float4 o0, o1;
        o0.x = fmaxf(acc[0], 0.f); o0.y = fmaxf(acc[1], 0.f);
        o0.z = fmaxf(acc[2], 0.f); o0.w = fmaxf(acc[3], 0.f);
        o1.x = fmaxf(acc[4], 0.f); o1.y = fmaxf(acc[5], 0.f);
        o1.z = fmaxf(acc[6], 0.f); o1.w = fmaxf(acc[7], 0.f);
        float4* op = (float4*)(h + (size_t)r * D1 + j0);
        op[0] = o0; op[1] = o1;
    }
}

// out = agg2 @ W2l + b2 + h @ W2r; LDS Wc[256][40]: rows 0..127 = W2r (h), 128..255 = W2l (agg2)
__global__ __launch_bounds__(320) void gemm2_kernel(
        const float* __restrict__ h, const float* __restrict__ agg,
        const float* __restrict__ W2l, const float* __restrict__ W2r,
        const float* __restrict__ b2, float* __restrict__ out, int N) {
    __shared__ float Wc[256 * 40];
    int t = threadIdx.x;
    {
        float4* wd = (float4*)Wc;
        const float4* wr = (const float4*)W2r;
        const float4* wl = (const float4*)W2l;
        for (int i = t; i < 2560; i += 320)
            wd[i] = (i < 1280) ? wr[i] : wl[i - 1280];
    }
    __syncthreads();
    int rl = t / 5;                 // 64 rows per tile
    int jc = t - rl * 5, j0 = jc * 8;
    float4 bb0 = ((const float4*)(b2 + j0))[0];
    float4 bb1 = ((const float4*)(b2 + j0))[1];
    int ntiles = (N + 63) >> 6;
    for (int tile = blockIdx.x; tile < ntiles; tile += gridDim.x) {
        int r = tile * 64 + rl;
        if (r >= N) continue;
        float acc[8] = {bb0.x, bb0.y, bb0.z, bb0.w, bb1.x, bb1.y, bb1.z, bb1.w};
        const float4* hr = (const float4*)(h + (size_t)r * D1);
#pragma unroll 8
        for (int k4 = 0; k4 < 32; ++k4) {
            float4 v = hr[k4];
            const float* wp = &Wc[(k4 * 4) * 40 + j0];
            MAC8(v.x, wp); MAC8(v.y, wp + 40); MAC8(v.z, wp + 80); MAC8(v.w, wp + 120);
        }
        const float4* ar = (const float4*)(agg + (size_t)r * D1);
#pragma unroll 8
        for (int k4 = 0; k4 < 32; ++k4) {
            float4 v = ar[k4];
            const float* wp = &Wc[(128 + k4 * 4) * 40 + j0];
            MAC8(v.x, wp); MAC8(v.y, wp + 40); MAC8(v.z, wp + 80); MAC8(v.w, wp + 120);
        }
        float4* op = (float4*)(out + (size_t)r * D2 + j0);
        float4 o0, o1;
        o0.x = acc[0]; o0.y = acc[1]; o0.z = acc[2]; o0.w = acc[3];
        o1.x = acc[4]; o1.y = acc[5]; o1.z = acc[6]; o1.w = acc[7];
        op[0] = o0; op[1] = o1;
    }
}

// ---------------- log_softmax over 40 columns, wave per row ----------------

__global__ void lsm_kernel(const float* __restrict__ h2, float* __restrict__ out, int N) {
    int wid = (blockIdx.x * blockDim.x + threadIdx.x) >> 6;
    int lane = threadIdx.x & 63;
    if (wid >= N) return;
    float v = (lane < D2) ? h2[(size_t)wid * D2 + lane] : -INFINITY;
    float m = v;
    for (int off = 32; off; off >>= 1) m = fmaxf(m, __shfl_xor(m, off));
    float p = (lane < D2) ? expf(v - m) : 0.f;
    float s = p;
    for (int off = 32; off; off >>= 1) s += __shfl_xor(s, off);
    if (lane < D2) out[(size_t)wid * D2 + lane] = v - m - logf(s);
}

// ---------------- launch ----------------

extern "C" void kernel_launch(void* const* d_in, const int* in_sizes, int n_in,
                              void* d_out, int out_size, void* d_ws, size_t ws_size,
                              hipStream_t stream) {
    const float* x   = (const float*)d_in[0];
    const int*   ei  = (const int*)d_in[1];
    const float* W1l = (const float*)d_in[2];
    const float* W1r = (const float*)d_in[3];
    const float* b1  = (const float*)d_in[4];
    const float* W2l = (const float*)d_in[5];
    const float* W2r = (const float*)d_in[6];
    const float* b2  = (const float*)d_in[7];
    float* out = (float*)d_out;

    const int N = N_NODES;
    const int E = in_sizes[1] / 2;
    const int* src = ei;
    const int* dst = ei + E;

    char* p = (char*)d_ws;
    auto alloc = [&](size_t bytes) -> void* {
        void* r = (void*)p;
        p += (bytes + 255) & ~(size_t)255;
        return r;
    };
    int*   deg    = (int*)alloc((size_t)N * 4);
    int*   rowptr = (int*)alloc((size_t)(N + 1) * 4);
    int*   cursor = (int*)alloc((size_t)N * 4);
    int*   csr    = (int*)alloc((size_t)E * 4);
    float* agg1b  = (float*)alloc((size_t)N * D0 * 4);
    float* hbuf   = (float*)alloc((size_t)N * D1 * 4);
    float* agg2b  = (float*)alloc((size_t)N * D1 * 4);

    hipMemsetAsync(deg, 0, (size_t)N * 4, stream);
    count_deg_kernel<<<(E + 255) / 256, 256, 0, stream>>>(dst, deg, E);
    scan_kernel<<<1, 1024, 0, stream>>>(deg, rowptr, cursor, N);
    fill_csr_kernel<<<(E + 255) / 256, 256, 0, stream>>>(src, dst, cursor, csr, E);

    // layer 1
    agg1_kernel<<<(N * 64 + 255) / 256, 256, 0, stream>>>(x, rowptr, csr, agg1b, N);
    gemm1_kernel<<<512, 256, 0, stream>>>(x, agg1b, W1l, W1r, b1, hbuf, N);

    // layer 2
    agg2_kernel<<<(N * 64 + 255) / 256, 256, 0, stream>>>(hbuf, rowptr, csr, agg2b, N);
    gemm2_kernel<<<512, 320, 0, stream>>>(hbuf, agg2b, W2l, W2r, b2, out, N);

    // log_softmax into second half of output
    lsm_kernel<<<(N * 64 + 255) / 256, 256, 0, stream>>>(out, out + (size_t)N * D2, N);
}

// Round 2
// 387.712 us; speedup vs baseline: 1.2535x; 1.2535x over previous
//
#include <hip/hip_runtime.h>
#include <math.h>

#define N_NODES 50000
#define N_EDGES 800000
#define D0 64
#define D1 128
#define D2 40

// ---------------- CSR build ----------------

__global__ void count_deg_kernel(const int* __restrict__ dst, int* __restrict__ deg, int E) {
    int e = blockIdx.x * blockDim.x + threadIdx.x;
    if (e < E) atomicAdd(&deg[dst[e]], 1);
}

// ---- hierarchical exclusive scan: deg[N] -> rowptr[N+1], cursor[N] ----
// stage A: per-block (256 elems) sums
__global__ void scanA_kernel(const int* __restrict__ deg, int* __restrict__ blocksum, int N) {
    __shared__ int sd[256];
    int t = threadIdx.x;
    int idx = blockIdx.x * 256 + t;
    int v = (idx < N) ? deg[idx] : 0;
    sd[t] = v;
    __syncthreads();
    for (int off = 128; off; off >>= 1) {
        if (t < off) sd[t] += sd[t + off];
        __syncthreads();
    }
    if (t == 0) blocksum[blockIdx.x] = sd[0];
}

// stage B: single small block scans the (<=256) block sums -> exclusive offsets
__global__ void scanB_kernel(const int* __restrict__ blocksum, int* __restrict__ blockoff,
                             int nb, int* __restrict__ rowptr, int N, int E) {
    __shared__ int sd[256];
    int t = threadIdx.x;
    int v = (t < nb) ? blocksum[t] : 0;
    sd[t] = v;
    __syncthreads();
    for (int off = 1; off < 256; off <<= 1) {
        int u = (t >= off) ? sd[t - off] : 0;
        __syncthreads();
        sd[t] += u;
        __syncthreads();
    }
    if (t < nb) blockoff[t] = sd[t] - v;   // exclusive
    if (t == 0) rowptr[N] = E;
}

// stage C: per-block local exclusive scan + block offset, write rowptr & cursor
__global__ void scanC_kernel(const int* __restrict__ deg, const int* __restrict__ blockoff,
                             int* __restrict__ rowptr, int* __restrict__ cursor, int N) {
    __shared__ int sd[256];
    int t = threadIdx.x;
    int idx = blockIdx.x * 256 + t;
    int v = (idx < N) ? deg[idx] : 0;
    sd[t] = v;
    __syncthreads();
    for (int off = 1; off < 256; off <<= 1) {
        int u = (t >= off) ? sd[t - off] : 0;
        __syncthreads();
        sd[t] += u;
        __syncthreads();
    }
    if (idx < N) {
        int ex = sd[t] - v + blockoff[blockIdx.x];
        rowptr[idx] = ex;
        cursor[idx] = ex;
    }
}

__global__ void fill_csr_kernel(const int* __restrict__ src, const int* __restrict__ dst,
                                int* __restrict__ cursor, int* __restrict__ csr, int E) {
    int e = blockIdx.x * blockDim.x + threadIdx.x;
    if (e < E) {
        int p = atomicAdd(&cursor[dst[e]], 1);
        csr[p] = src[e];
    }
}

// ---------------- aggregation (mean over incoming edges) ----------------

// one wave per node, D0=64: lane = feature index
__global__ void agg1_kernel(const float* __restrict__ x, const int* __restrict__ rowptr,
                            const int* __restrict__ csr, float* __restrict__ agg, int N) {
    int wid = (blockIdx.x * blockDim.x + threadIdx.x) >> 6;
    int lane = threadIdx.x & 63;
    if (wid >= N) return;
    int beg = rowptr[wid], end = rowptr[wid + 1];
    float acc = 0.f;
    for (int base = beg; base < end; base += 64) {
        int cnt = min(64, end - base);
        int sl = (base + lane < end) ? csr[base + lane] : 0;
        for (int i = 0; i < cnt; ++i) {
            int s = __shfl(sl, i);
            acc += x[(size_t)s * D0 + lane];
        }
    }
    float d = (float)max(end - beg, 1);
    agg[(size_t)wid * D0 + lane] = acc / d;
}

// one wave per node, D1=128: lane handles float2 at column 2*lane
__global__ void agg2_kernel(const float* __restrict__ h, const int* __restrict__ rowptr,
                            const int* __restrict__ csr, float* __restrict__ agg, int N) {
    int wid = (blockIdx.x * blockDim.x + threadIdx.x) >> 6;
    int lane = threadIdx.x & 63;
    if (wid >= N) return;
    int beg = rowptr[wid], end = rowptr[wid + 1];
    float ax = 0.f, ay = 0.f;
    for (int base = beg; base < end; base += 64) {
        int cnt = min(64, end - base);
        int sl = (base + lane < end) ? csr[base + lane] : 0;
        for (int i = 0; i < cnt; ++i) {
            int s = __shfl(sl, i);
            float2 v = ((const float2*)(h + (size_t)s * D1))[lane];
            ax += v.x;
            ay += v.y;
        }
    }
    float inv = 1.f / (float)max(end - beg, 1);
    float2 o; o.x = ax * inv; o.y = ay * inv;
    ((float2*)(agg + (size_t)wid * D1))[lane] = o;
}

// ---------------- GEMMs (fp32 vector ALU; no f32 MFMA on CDNA4) ----------------

#define MAC8(vs, wp) {                                              \
    float4 w0 = *(const float4*)(wp);                               \
    float4 w1 = *(const float4*)((wp) + 4);                         \
    acc[0] += (vs) * w0.x; acc[1] += (vs) * w0.y;                   \
    acc[2] += (vs) * w0.z; acc[3] += (vs) * w0.w;                   \
    acc[4] += (vs) * w1.x; acc[5] += (vs) * w1.y;                   \
    acc[6] += (vs) * w1.z; acc[7] += (vs) * w1.w; }

// h = relu(agg1 @ W1l + b1 + x @ W1r); LDS holds Wc[128][128]:
// rows 0..63 = W1r (multiplies x), rows 64..127 = W1l (multiplies agg1)
__global__ __launch_bounds__(256) void gemm1_kernel(
        const float* __restrict__ x, const float* __restrict__ agg,
        const float* __restrict__ W1l, const float* __restrict__ W1r,
        const float* __restrict__ b1, float* __restrict__ h, int N) {
    __shared__ float Wc[128 * 128];
    int t = threadIdx.x;
    {
        float4* wd = (float4*)Wc;
        const float4* wr = (const float4*)W1r;
        const float4* wl = (const float4*)W1l;
        for (int i = t; i < 4096; i += 256)
            wd[i] = (i < 2048) ? wr[i] : wl[i - 2048];
    }
    __syncthreads();
    int jc = t & 15, j0 = jc * 8;
    int rlocal = t >> 4;           // 16 rows per tile
    float4 bb0 = ((const float4*)(b1 + j0))[0];
    float4 bb1 = ((const float4*)(b1 + j0))[1];
    int ntiles = (N + 15) >> 4;
    for (int tile = blockIdx.x; tile < ntiles; tile += gridDim.x) {
        int r = tile * 16 + rlocal;
        if (r >= N) continue;
        float acc[8] = {bb0.x, bb0.y, bb0.z, bb0.w, bb1.x, bb1.y, bb1.z, bb1.w};
        const float4* xr = (const float4*)(x + (size_t)r * D0);
#pragma unroll
        for (int k4 = 0; k4 < 16; ++k4) {
            float4 v = xr[k4];
            const float* wp = &Wc[(k4 * 4) * 128 + j0];
            MAC8(v.x, wp); MAC8(v.y, wp + 128); MAC8(v.z, wp + 256); MAC8(v.w, wp + 384);
        }
        const float4* ar = (const float4*)(agg + (size_t)r * D0);
#pragma unroll
        for (int k4 = 0; k4 < 16; ++k4) {
            float4 v = ar[k4];
            const float* wp = &Wc[(64 + k4 * 4) * 128 + j0];
            MAC8(v.x, wp); MAC8(v.y, wp + 128); MAC8(v.z, wp + 256); MAC8(v.w, wp + 384);
        }
        float4 o0, o1;
        o0.x = fmaxf(acc[0], 0.f); o0.y = fmaxf(acc[1], 0.f);
        o0.z = fmaxf(acc[2], 0.f); o0.w = fmaxf(acc[3], 0.f);
        o1.x = fmaxf(acc[4], 0.f); o1.y = fmaxf(acc[5], 0.f);
        o1.z = fmaxf(acc[6], 0.f); o1.w = fmaxf(acc[7], 0.f);
        float4* op = (float4*)(h + (size_t)r * D1 + j0);
        op[0] = o0; op[1] = o1;
    }
}

// out = agg2 @ W2l + b2 + h @ W2r; LDS Wc[256][40]: rows 0..127 = W2r (h), 128..255 = W2l (agg2)
__global__ __launch_bounds__(320) void gemm2_kernel(
        const float* __restrict__ h, const float* __restrict__ agg,
        const float* __restrict__ W2l, const float* __restrict__ W2r,
        const float* __restrict__ b2, float* __restrict__ out, int N) {
    __shared__ float Wc[256 * 40];
    int t = threadIdx.x;
    {
        float4* wd = (float4*)Wc;
        const float4* wr = (const float4*)W2r;
        const float4* wl = (const float4*)W2l;
        for (int i = t; i < 2560; i += 320)
            wd[i] = (i < 1280) ? wr[i] : wl[i - 1280];
    }
    __syncthreads();
    int rl = t / 5;                 // 64 rows per tile
    int jc = t - rl * 5, j0 = jc * 8;
    float4 bb0 = ((const float4*)(b2 + j0))[0];
    float4 bb1 = ((const float4*)(b2 + j0))[1];
    int ntiles = (N + 63) >> 6;
    for (int tile = blockIdx.x; tile < ntiles; tile += gridDim.x) {
        int r = tile * 64 + rl;
        if (r >= N) continue;
        float acc[8] = {bb0.x, bb0.y, bb0.z, bb0.w, bb1.x, bb1.y, bb1.z, bb1.w};
        const float4* hr = (const float4*)(h + (size_t)r * D1);
#pragma unroll 8
        for (int k4 = 0; k4 < 32; ++k4) {
            float4 v = hr[k4];
            const float* wp = &Wc[(k4 * 4) * 40 + j0];
            MAC8(v.x, wp); MAC8(v.y, wp + 40); MAC8(v.z, wp + 80); MAC8(v.w, wp + 120);
        }
        const float4* ar = (const float4*)(agg + (size_t)r * D1);
#pragma unroll 8
        for (int k4 = 0; k4 < 32; ++k4) {
            float4 v = ar[k4];
            const float* wp = &Wc[(128 + k4 * 4) * 40 + j0];
            MAC8(v.x, wp); MAC8(v.y, wp + 40); MAC8(v.z, wp + 80); MAC8(v.w, wp + 120);
        }
        float4* op = (float4*)(out + (size_t)r * D2 + j0);
        float4 o0, o1;
        o0.x = acc[0]; o0.y = acc[1]; o0.z = acc[2]; o0.w = acc[3];
        o1.x = acc[4]; o1.y = acc[5]; o1.z = acc[6]; o1.w = acc[7];
        op[0] = o0; op[1] = o1;
    }
}

// ---------------- log_softmax over 40 columns, wave per row ----------------

__global__ void lsm_kernel(const float* __restrict__ h2, float* __restrict__ out, int N) {
    int wid = (blockIdx.x * blockDim.x + threadIdx.x) >> 6;
    int lane = threadIdx.x & 63;
    if (wid >= N) return;
    float v = (lane < D2) ? h2[(size_t)wid * D2 + lane] : -INFINITY;
    float m = v;
    for (int off = 32; off; off >>= 1) m = fmaxf(m, __shfl_xor(m, off));
    float p = (lane < D2) ? expf(v - m) : 0.f;
    float s = p;
    for (int off = 32; off; off >>= 1) s += __shfl_xor(s, off);
    if (lane < D2) out[(size_t)wid * D2 + lane] = v - m - logf(s);
}

// ---------------- launch ----------------

extern "C" void kernel_launch(void* const* d_in, const int* in_sizes, int n_in,
                              void* d_out, int out_size, void* d_ws, size_t ws_size,
                              hipStream_t stream) {
    const float* x   = (const float*)d_in[0];
    const int*   ei  = (const int*)d_in[1];
    const float* W1l = (const float*)d_in[2];
    const float* W1r = (const float*)d_in[3];
    const float* b1  = (const float*)d_in[4];
    const float* W2l = (const float*)d_in[5];
    const float* W2r = (const float*)d_in[6];
    const float* b2  = (const float*)d_in[7];
    float* out = (float*)d_out;

    const int N = N_NODES;
    const int E = in_sizes[1] / 2;
    const int* src = ei;
    const int* dst = ei + E;

    char* p = (char*)d_ws;
    auto alloc = [&](size_t bytes) -> void* {
        void* r = (void*)p;
        p += (bytes + 255) & ~(size_t)255;
        return r;
    };
    int*   deg      = (int*)alloc((size_t)N * 4);
    int*   rowptr   = (int*)alloc((size_t)(N + 1) * 4);
    int*   cursor   = (int*)alloc((size_t)N * 4);
    int*   csr      = (int*)alloc((size_t)E * 4);
    int*   blocksum = (int*)alloc(256 * 4);
    int*   blockoff = (int*)alloc(256 * 4);
    float* agg1b    = (float*)alloc((size_t)N * D0 * 4);
    float* hbuf     = (float*)alloc((size_t)N * D1 * 4);
    float* agg2b    = (float*)alloc((size_t)N * D1 * 4);

    const int nb = (N + 255) / 256;   // 196 <= 256

    hipMemsetAsync(deg, 0, (size_t)N * 4, stream);
    count_deg_kernel<<<(E + 255) / 256, 256, 0, stream>>>(dst, deg, E);
    scanA_kernel<<<nb, 256, 0, stream>>>(deg, blocksum, N);
    scanB_kernel<<<1, 256, 0, stream>>>(blocksum, blockoff, nb, rowptr, N, E);
    scanC_kernel<<<nb, 256, 0, stream>>>(deg, blockoff, rowptr, cursor, N);
    fill_csr_kernel<<<(E + 255) / 256, 256, 0, stream>>>(src, dst, cursor, csr, E);

    // layer 1
    agg1_kernel<<<(N * 64 + 255) / 256, 256, 0, stream>>>(x, rowptr, csr, agg1b, N);
    gemm1_kernel<<<512, 256, 0, stream>>>(x, agg1b, W1l, W1r, b1, hbuf, N);

    // layer 2
    agg2_kernel<<<(N * 64 + 255) / 256, 256, 0, stream>>>(hbuf, rowptr, csr, agg2b, N);
    gemm2_kernel<<<512, 320, 0, stream>>>(hbuf, agg2b, W2l, W2r, b2, out, N);

    // log_softmax into second half of output
    lsm_kernel<<<(N * 64 + 255) / 256, 256, 0, stream>>>(out, out + (size_t)N * D2, N);
}

// Round 3
// 359.002 us; speedup vs baseline: 1.3537x; 1.0800x over previous
//
#include <hip/hip_runtime.h>
#include <math.h>

#define N_NODES 50000
#define N_EDGES 800000
#define D0 64
#define D1 128
#define D2 40

// ---------------- CSR build ----------------

__global__ void count_deg_kernel(const int* __restrict__ dst, int* __restrict__ deg, int E) {
    int e = blockIdx.x * blockDim.x + threadIdx.x;
    if (e < E) atomicAdd(&deg[dst[e]], 1);
}

// ---- hierarchical exclusive scan: deg[N] -> rowptr[N+1], cursor[N] ----
__global__ void scanA_kernel(const int* __restrict__ deg, int* __restrict__ blocksum, int N) {
    __shared__ int sd[256];
    int t = threadIdx.x;
    int idx = blockIdx.x * 256 + t;
    int v = (idx < N) ? deg[idx] : 0;
    sd[t] = v;
    __syncthreads();
    for (int off = 128; off; off >>= 1) {
        if (t < off) sd[t] += sd[t + off];
        __syncthreads();
    }
    if (t == 0) blocksum[blockIdx.x] = sd[0];
}

__global__ void scanB_kernel(const int* __restrict__ blocksum, int* __restrict__ blockoff,
                             int nb, int* __restrict__ rowptr, int N, int E) {
    __shared__ int sd[256];
    int t = threadIdx.x;
    int v = (t < nb) ? blocksum[t] : 0;
    sd[t] = v;
    __syncthreads();
    for (int off = 1; off < 256; off <<= 1) {
        int u = (t >= off) ? sd[t - off] : 0;
        __syncthreads();
        sd[t] += u;
        __syncthreads();
    }
    if (t < nb) blockoff[t] = sd[t] - v;   // exclusive
    if (t == 0) rowptr[N] = E;
}

__global__ void scanC_kernel(const int* __restrict__ deg, const int* __restrict__ blockoff,
                             int* __restrict__ rowptr, int* __restrict__ cursor, int N) {
    __shared__ int sd[256];
    int t = threadIdx.x;
    int idx = blockIdx.x * 256 + t;
    int v = (idx < N) ? deg[idx] : 0;
    sd[t] = v;
    __syncthreads();
    for (int off = 1; off < 256; off <<= 1) {
        int u = (t >= off) ? sd[t - off] : 0;
        __syncthreads();
        sd[t] += u;
        __syncthreads();
    }
    if (idx < N) {
        int ex = sd[t] - v + blockoff[blockIdx.x];
        rowptr[idx] = ex;
        cursor[idx] = ex;
    }
}

__global__ void fill_csr_kernel(const int* __restrict__ src, const int* __restrict__ dst,
                                int* __restrict__ cursor, int* __restrict__ csr, int E) {
    int e = blockIdx.x * blockDim.x + threadIdx.x;
    if (e < E) {
        int p = atomicAdd(&cursor[dst[e]], 1);
        csr[p] = src[e];
    }
}

// ---------------- aggregation (mean over incoming edges) ----------------

__global__ void agg1_kernel(const float* __restrict__ x, const int* __restrict__ rowptr,
                            const int* __restrict__ csr, float* __restrict__ agg, int N) {
    int wid = (blockIdx.x * blockDim.x + threadIdx.x) >> 6;
    int lane = threadIdx.x & 63;
    if (wid >= N) return;
    int beg = rowptr[wid], end = rowptr[wid + 1];
    float acc = 0.f;
    for (int base = beg; base < end; base += 64) {
        int cnt = min(64, end - base);
        int sl = (base + lane < end) ? csr[base + lane] : 0;
        for (int i = 0; i < cnt; ++i) {
            int s = __shfl(sl, i);
            acc += x[(size_t)s * D0 + lane];
        }
    }
    float d = (float)max(end - beg, 1);
    agg[(size_t)wid * D0 + lane] = acc / d;
}

__global__ void agg2_kernel(const float* __restrict__ h, const int* __restrict__ rowptr,
                            const int* __restrict__ csr, float* __restrict__ agg, int N) {
    int wid = (blockIdx.x * blockDim.x + threadIdx.x) >> 6;
    int lane = threadIdx.x & 63;
    if (wid >= N) return;
    int beg = rowptr[wid], end = rowptr[wid + 1];
    float ax = 0.f, ay = 0.f;
    for (int base = beg; base < end; base += 64) {
        int cnt = min(64, end - base);
        int sl = (base + lane < end) ? csr[base + lane] : 0;
        for (int i = 0; i < cnt; ++i) {
            int s = __shfl(sl, i);
            float2 v = ((const float2*)(h + (size_t)s * D1))[lane];
            ax += v.x;
            ay += v.y;
        }
    }
    float inv = 1.f / (float)max(end - beg, 1);
    float2 o; o.x = ax * inv; o.y = ay * inv;
    ((float2*)(agg + (size_t)wid * D1))[lane] = o;
}

// ---------------- GEMMs: register row-blocking, 1 ds_read_b128 feeds 32 FMAs ----------------

// h = relu(concat-GEMM + b1). Thread: 8 rows x 4 cols. Block 256 = 32 colchunks x 8 rowgroups.
// Tile = 64 rows. Wc[128][128]: rows 0..63 = W1r (x), rows 64..127 = W1l (agg).
__global__ __launch_bounds__(256) void gemm1_kernel(
        const float* __restrict__ x, const float* __restrict__ agg,
        const float* __restrict__ W1l, const float* __restrict__ W1r,
        const float* __restrict__ b1, float* __restrict__ h, int N) {
    __shared__ float Wc[128 * 128];
    int t = threadIdx.x;
    {
        float4* wd = (float4*)Wc;
        const float4* wr = (const float4*)W1r;
        const float4* wl = (const float4*)W1l;
        for (int i = t; i < 4096; i += 256)
            wd[i] = (i < 2048) ? wr[i] : wl[i - 2048];
    }
    __syncthreads();
    int jc = t & 31, j0 = jc * 4;
    int rg = t >> 5;                       // 0..7, 8 rows each -> 64 rows/tile
    float4 bb = *(const float4*)(b1 + j0);
    int ntiles = (N + 63) >> 6;
    for (int tile = blockIdx.x; tile < ntiles; tile += gridDim.x) {
        int r0 = tile * 64 + rg * 8;
        size_t roff[8];
#pragma unroll
        for (int i = 0; i < 8; ++i) {
            int r = r0 + i;
            roff[i] = (size_t)((r < N) ? r : (N - 1)) * D0;   // clamp (stores guarded)
        }
        float acc[8][4];
#pragma unroll
        for (int i = 0; i < 8; ++i) {
            acc[i][0] = bb.x; acc[i][1] = bb.y; acc[i][2] = bb.z; acc[i][3] = bb.w;
        }
#pragma unroll 1
        for (int ph = 0; ph < 2; ++ph) {
            const float* inp = ph ? agg : x;
            const float* wbase = &Wc[(ph * 64) * 128 + j0];
#pragma unroll 2
            for (int k4 = 0; k4 < 16; ++k4) {
                float4 v[8];
#pragma unroll
                for (int i = 0; i < 8; ++i)
                    v[i] = *(const float4*)(inp + roff[i] + k4 * 4);
#pragma unroll
                for (int kk = 0; kk < 4; ++kk) {
                    float4 w = *(const float4*)(wbase + (k4 * 4 + kk) * 128);
#pragma unroll
                    for (int i = 0; i < 8; ++i) {
                        float s = ((const float*)&v[i])[kk];
                        acc[i][0] += s * w.x; acc[i][1] += s * w.y;
                        acc[i][2] += s * w.z; acc[i][3] += s * w.w;
                    }
                }
            }
        }
#pragma unroll
        for (int i = 0; i < 8; ++i) {
            int r = r0 + i;
            if (r < N) {
                float4 o;
                o.x = fmaxf(acc[i][0], 0.f); o.y = fmaxf(acc[i][1], 0.f);
                o.z = fmaxf(acc[i][2], 0.f); o.w = fmaxf(acc[i][3], 0.f);
                *(float4*)(h + (size_t)r * D1 + j0) = o;
            }
        }
    }
}

// out = concat-GEMM + b2. Thread: 4 rows x 4 cols. Block 320 = 10 colchunks x 32 rowgroups.
// Tile = 128 rows. Wc[256][40]: rows 0..127 = W2r (h), rows 128..255 = W2l (agg).
__global__ __launch_bounds__(320) void gemm2_kernel(
        const float* __restrict__ h, const float* __restrict__ agg,
        const float* __restrict__ W2l, const float* __restrict__ W2r,
        const float* __restrict__ b2, float* __restrict__ out, int N) {
    __shared__ float Wc[256 * 40];
    int t = threadIdx.x;
    {
        float4* wd = (float4*)Wc;
        const float4* wr = (const float4*)W2r;
        const float4* wl = (const float4*)W2l;
        for (int i = t; i < 2560; i += 320)
            wd[i] = (i < 1280) ? wr[i] : wl[i - 1280];
    }
    __syncthreads();
    int jc = t % 10, j0 = jc * 4;
    int rg = t / 10;                       // 0..31, 4 rows each -> 128 rows/tile
    float4 bb = *(const float4*)(b2 + j0);
    int ntiles = (N + 127) >> 7;
    for (int tile = blockIdx.x; tile < ntiles; tile += gridDim.x) {
        int r0 = tile * 128 + rg * 4;
        size_t roff[4];
#pragma unroll
        for (int i = 0; i < 4; ++i) {
            int r = r0 + i;
            roff[i] = (size_t)((r < N) ? r : (N - 1)) * D1;
        }
        float acc[4][4];
#pragma unroll
        for (int i = 0; i < 4; ++i) {
            acc[i][0] = bb.x; acc[i][1] = bb.y; acc[i][2] = bb.z; acc[i][3] = bb.w;
        }
#pragma unroll 1
        for (int ph = 0; ph < 2; ++ph) {
            const float* inp = ph ? agg : h;
            const float* wbase = &Wc[(ph * 128) * 40 + j0];
#pragma unroll 2
            for (int k4 = 0; k4 < 32; ++k4) {
                float4 v[4];
#pragma unroll
                for (int i = 0; i < 4; ++i)
                    v[i] = *(const float4*)(inp + roff[i] + k4 * 4);
#pragma unroll
                for (int kk = 0; kk < 4; ++kk) {
                    float4 w = *(const float4*)(wbase + (k4 * 4 + kk) * 40);
#pragma unroll
                    for (int i = 0; i < 4; ++i) {
                        float s = ((const float*)&v[i])[kk];
                        acc[i][0] += s * w.x; acc[i][1] += s * w.y;
                        acc[i][2] += s * w.z; acc[i][3] += s * w.w;
                    }
                }
            }
        }
#pragma unroll
        for (int i = 0; i < 4; ++i) {
            int r = r0 + i;
            if (r < N) {
                float4 o;
                o.x = acc[i][0]; o.y = acc[i][1]; o.z = acc[i][2]; o.w = acc[i][3];
                *(float4*)(out + (size_t)r * D2 + j0) = o;
            }
        }
    }
}

// ---------------- log_softmax over 40 columns, wave per row ----------------

__global__ void lsm_kernel(const float* __restrict__ h2, float* __restrict__ out, int N) {
    int wid = (blockIdx.x * blockDim.x + threadIdx.x) >> 6;
    int lane = threadIdx.x & 63;
    if (wid >= N) return;
    float v = (lane < D2) ? h2[(size_t)wid * D2 + lane] : -INFINITY;
    float m = v;
    for (int off = 32; off; off >>= 1) m = fmaxf(m, __shfl_xor(m, off));
    float p = (lane < D2) ? expf(v - m) : 0.f;
    float s = p;
    for (int off = 32; off; off >>= 1) s += __shfl_xor(s, off);
    if (lane < D2) out[(size_t)wid * D2 + lane] = v - m - logf(s);
}

// ---------------- launch ----------------

extern "C" void kernel_launch(void* const* d_in, const int* in_sizes, int n_in,
                              void* d_out, int out_size, void* d_ws, size_t ws_size,
                              hipStream_t stream) {
    const float* x   = (const float*)d_in[0];
    const int*   ei  = (const int*)d_in[1];
    const float* W1l = (const float*)d_in[2];
    const float* W1r = (const float*)d_in[3];
    const float* b1  = (const float*)d_in[4];
    const float* W2l = (const float*)d_in[5];
    const float* W2r = (const float*)d_in[6];
    const float* b2  = (const float*)d_in[7];
    float* out = (float*)d_out;

    const int N = N_NODES;
    const int E = in_sizes[1] / 2;
    const int* src = ei;
    const int* dst = ei + E;

    char* p = (char*)d_ws;
    auto alloc = [&](size_t bytes) -> void* {
        void* r = (void*)p;
        p += (bytes + 255) & ~(size_t)255;
        return r;
    };
    int*   deg      = (int*)alloc((size_t)N * 4);
    int*   rowptr   = (int*)alloc((size_t)(N + 1) * 4);
    int*   cursor   = (int*)alloc((size_t)N * 4);
    int*   csr      = (int*)alloc((size_t)E * 4);
    int*   blocksum = (int*)alloc(256 * 4);
    int*   blockoff = (int*)alloc(256 * 4);
    float* agg1b    = (float*)alloc((size_t)N * D0 * 4);
    float* hbuf     = (float*)alloc((size_t)N * D1 * 4);
    float* agg2b    = (float*)alloc((size_t)N * D1 * 4);

    const int nb = (N + 255) / 256;   // 196 <= 256

    hipMemsetAsync(deg, 0, (size_t)N * 4, stream);
    count_deg_kernel<<<(E + 255) / 256, 256, 0, stream>>>(dst, deg, E);
    scanA_kernel<<<nb, 256, 0, stream>>>(deg, blocksum, N);
    scanB_kernel<<<1, 256, 0, stream>>>(blocksum, blockoff, nb, rowptr, N, E);
    scanC_kernel<<<nb, 256, 0, stream>>>(deg, blockoff, rowptr, cursor, N);
    fill_csr_kernel<<<(E + 255) / 256, 256, 0, stream>>>(src, dst, cursor, csr, E);

    // layer 1
    agg1_kernel<<<(N * 64 + 255) / 256, 256, 0, stream>>>(x, rowptr, csr, agg1b, N);
    gemm1_kernel<<<(N + 63) / 64, 256, 0, stream>>>(x, agg1b, W1l, W1r, b1, hbuf, N);

    // layer 2
    agg2_kernel<<<(N * 64 + 255) / 256, 256, 0, stream>>>(hbuf, rowptr, csr, agg2b, N);
    gemm2_kernel<<<(N + 127) / 128, 320, 0, stream>>>(hbuf, agg2b, W2l, W2r, b2, out, N);

    // log_softmax into second half of output
    lsm_kernel<<<(N * 64 + 255) / 256, 256, 0, stream>>>(out, out + (size_t)N * D2, N);
}

// Round 4
// 351.305 us; speedup vs baseline: 1.3834x; 1.0219x over previous
//
#include <hip/hip_runtime.h>
#include <hip/hip_bf16.h>
#include <math.h>

#define N_NODES 50000
#define N_EDGES 800000
#define D0 64
#define D1 128
#define D2 40

// ---------------- CSR build ----------------

__global__ void count_deg_kernel(const int* __restrict__ dst, int* __restrict__ deg, int E) {
    int e = blockIdx.x * blockDim.x + threadIdx.x;
    if (e < E) atomicAdd(&deg[dst[e]], 1);
}

__global__ void scanA_kernel(const int* __restrict__ deg, int* __restrict__ blocksum, int N) {
    __shared__ int sd[256];
    int t = threadIdx.x;
    int idx = blockIdx.x * 256 + t;
    int v = (idx < N) ? deg[idx] : 0;
    sd[t] = v;
    __syncthreads();
    for (int off = 128; off; off >>= 1) {
        if (t < off) sd[t] += sd[t + off];
        __syncthreads();
    }
    if (t == 0) blocksum[blockIdx.x] = sd[0];
}

__global__ void scanB_kernel(const int* __restrict__ blocksum, int* __restrict__ blockoff,
                             int nb, int* __restrict__ rowptr, int N, int E) {
    __shared__ int sd[256];
    int t = threadIdx.x;
    int v = (t < nb) ? blocksum[t] : 0;
    sd[t] = v;
    __syncthreads();
    for (int off = 1; off < 256; off <<= 1) {
        int u = (t >= off) ? sd[t - off] : 0;
        __syncthreads();
        sd[t] += u;
        __syncthreads();
    }
    if (t < nb) blockoff[t] = sd[t] - v;
    if (t == 0) rowptr[N] = E;
}

__global__ void scanC_kernel(const int* __restrict__ deg, const int* __restrict__ blockoff,
                             int* __restrict__ rowptr, int* __restrict__ cursor, int N) {
    __shared__ int sd[256];
    int t = threadIdx.x;
    int idx = blockIdx.x * 256 + t;
    int v = (idx < N) ? deg[idx] : 0;
    sd[t] = v;
    __syncthreads();
    for (int off = 1; off < 256; off <<= 1) {
        int u = (t >= off) ? sd[t - off] : 0;
        __syncthreads();
        sd[t] += u;
        __syncthreads();
    }
    if (idx < N) {
        int ex = sd[t] - v + blockoff[blockIdx.x];
        rowptr[idx] = ex;
        cursor[idx] = ex;
    }
}

__global__ void fill_csr_kernel(const int* __restrict__ src, const int* __restrict__ dst,
                                int* __restrict__ cursor, int* __restrict__ csr, int E) {
    int e = blockIdx.x * blockDim.x + threadIdx.x;
    if (e < E) {
        int p = atomicAdd(&cursor[dst[e]], 1);
        csr[p] = src[e];
    }
}

// ---------------- cast x to bf16 (halves agg1 gather bytes) ----------------

__global__ void cast_x_kernel(const float* __restrict__ x, __hip_bfloat16* __restrict__ xh, int n) {
    int i = (blockIdx.x * blockDim.x + threadIdx.x) * 4;
    if (i < n) {
        float4 v = *(const float4*)(x + i);
        xh[i + 0] = __float2bfloat16(v.x);
        xh[i + 1] = __float2bfloat16(v.y);
        xh[i + 2] = __float2bfloat16(v.z);
        xh[i + 3] = __float2bfloat16(v.w);
    }
}

// ---------------- aggregation layer 1: gather bf16 x, fp32 accumulate ----------------

__global__ void agg1_kernel(const __hip_bfloat16* __restrict__ xh, const int* __restrict__ rowptr,
                            const int* __restrict__ csr, float* __restrict__ agg, int N) {
    int wid = (blockIdx.x * blockDim.x + threadIdx.x) >> 6;
    int lane = threadIdx.x & 63;
    if (wid >= N) return;
    int beg = rowptr[wid], end = rowptr[wid + 1];
    float acc = 0.f;
    for (int base = beg; base < end; base += 64) {
        int cnt = min(64, end - base);
        int sl = (base + lane < end) ? csr[base + lane] : 0;
        for (int i = 0; i < cnt; ++i) {
            int s = __shfl(sl, i);
            acc += __bfloat162float(xh[(size_t)s * D0 + lane]);
        }
    }
    float d = (float)max(end - beg, 1);
    agg[(size_t)wid * D0 + lane] = acc / d;
}

// ---------------- layer-2 aggregation on PROJECTED features (linearity trick) ----------------
// out[v] = r2[v] + mean_{src->v} p2[src]   where p2 = h@W2l, r2 = h@W2r + b2

__global__ void agg2_kernel(const float* __restrict__ p2, const float* __restrict__ r2,
                            const int* __restrict__ rowptr, const int* __restrict__ csr,
                            float* __restrict__ out, int N) {
    int wid = (blockIdx.x * blockDim.x + threadIdx.x) >> 6;
    int lane = threadIdx.x & 63;
    if (wid >= N) return;
    int beg = rowptr[wid], end = rowptr[wid + 1];
    bool act = lane < D2;
    float acc = 0.f;
    for (int base = beg; base < end; base += 64) {
        int cnt = min(64, end - base);
        int sl = (base + lane < end) ? csr[base + lane] : 0;
        for (int i = 0; i < cnt; ++i) {
            int s = __shfl(sl, i);
            if (act) acc += p2[(size_t)s * D2 + lane];
        }
    }
    float inv = 1.f / (float)max(end - beg, 1);
    if (act) out[(size_t)wid * D2 + lane] = r2[(size_t)wid * D2 + lane] + acc * inv;
}

// ---------------- GEMM 1: h = relu(x@W1r + agg1@W1l + b1) ----------------
// Thread: 8 rows x 4 cols; block 256 = 32 colchunks x 8 rowgroups; tile 64 rows.
__global__ __launch_bounds__(256) void gemm1_kernel(
        const float* __restrict__ x, const float* __restrict__ agg,
        const float* __restrict__ W1l, const float* __restrict__ W1r,
        const float* __restrict__ b1, float* __restrict__ h, int N) {
    __shared__ float Wc[128 * 128];   // rows 0..63 = W1r (x), 64..127 = W1l (agg)
    int t = threadIdx.x;
    {
        float4* wd = (float4*)Wc;
        const float4* wr = (const float4*)W1r;
        const float4* wl = (const float4*)W1l;
        for (int i = t; i < 4096; i += 256)
            wd[i] = (i < 2048) ? wr[i] : wl[i - 2048];
    }
    __syncthreads();
    int jc = t & 31, j0 = jc * 4;
    int rg = t >> 5;
    float4 bb = *(const float4*)(b1 + j0);
    int ntiles = (N + 63) >> 6;
    for (int tile = blockIdx.x; tile < ntiles; tile += gridDim.x) {
        int r0 = tile * 64 + rg * 8;
        size_t roff[8];
#pragma unroll
        for (int i = 0; i < 8; ++i) {
            int r = r0 + i;
            roff[i] = (size_t)((r < N) ? r : (N - 1)) * D0;
        }
        float acc[8][4];
#pragma unroll
        for (int i = 0; i < 8; ++i) {
            acc[i][0] = bb.x; acc[i][1] = bb.y; acc[i][2] = bb.z; acc[i][3] = bb.w;
        }
#pragma unroll 1
        for (int ph = 0; ph < 2; ++ph) {
            const float* inp = ph ? agg : x;
            const float* wbase = &Wc[(ph * 64) * 128 + j0];
#pragma unroll 2
            for (int k4 = 0; k4 < 16; ++k4) {
                float4 v[8];
#pragma unroll
                for (int i = 0; i < 8; ++i)
                    v[i] = *(const float4*)(inp + roff[i] + k4 * 4);
#pragma unroll
                for (int kk = 0; kk < 4; ++kk) {
                    float4 w = *(const float4*)(wbase + (k4 * 4 + kk) * 128);
#pragma unroll
                    for (int i = 0; i < 8; ++i) {
                        float s = ((const float*)&v[i])[kk];
                        acc[i][0] += s * w.x; acc[i][1] += s * w.y;
                        acc[i][2] += s * w.z; acc[i][3] += s * w.w;
                    }
                }
            }
        }
#pragma unroll
        for (int i = 0; i < 8; ++i) {
            int r = r0 + i;
            if (r < N) {
                float4 o;
                o.x = fmaxf(acc[i][0], 0.f); o.y = fmaxf(acc[i][1], 0.f);
                o.z = fmaxf(acc[i][2], 0.f); o.w = fmaxf(acc[i][3], 0.f);
                *(float4*)(h + (size_t)r * D1 + j0) = o;
            }
        }
    }
}

// ---------------- GEMM 2: p2 = h@W2l, r2 = h@W2r + b2 (one pass over h) ----------------
// Thread: 4 rows x 4 cols x 2 outputs; block 320 = 10 colchunks x 32 rowgroups; tile 128 rows.
__global__ __launch_bounds__(320) void gemm2_kernel(
        const float* __restrict__ h,
        const float* __restrict__ W2l, const float* __restrict__ W2r,
        const float* __restrict__ b2,
        float* __restrict__ p2, float* __restrict__ r2, int N) {
    __shared__ float Wl[128 * 40];
    __shared__ float Wr[128 * 40];
    int t = threadIdx.x;
    {
        float4* a = (float4*)Wl;
        float4* b = (float4*)Wr;
        const float4* sa = (const float4*)W2l;
        const float4* sb = (const float4*)W2r;
        for (int i = t; i < 1280; i += 320) { a[i] = sa[i]; b[i] = sb[i]; }
    }
    __syncthreads();
    int jc = t % 10, j0 = jc * 4;
    int rg = t / 10;
    float4 bb = *(const float4*)(b2 + j0);
    int ntiles = (N + 127) >> 7;
    for (int tile = blockIdx.x; tile < ntiles; tile += gridDim.x) {
        int r0 = tile * 128 + rg * 4;
        size_t roff[4];
#pragma unroll
        for (int i = 0; i < 4; ++i) {
            int r = r0 + i;
            roff[i] = (size_t)((r < N) ? r : (N - 1)) * D1;
        }
        float accp[4][4], accr[4][4];
#pragma unroll
        for (int i = 0; i < 4; ++i) {
            accp[i][0] = 0.f; accp[i][1] = 0.f; accp[i][2] = 0.f; accp[i][3] = 0.f;
            accr[i][0] = bb.x; accr[i][1] = bb.y; accr[i][2] = bb.z; accr[i][3] = bb.w;
        }
#pragma unroll 2
        for (int k4 = 0; k4 < 32; ++k4) {
            float4 v[4];
#pragma unroll
            for (int i = 0; i < 4; ++i)
                v[i] = *(const float4*)(h + roff[i] + k4 * 4);
#pragma unroll
            for (int kk = 0; kk < 4; ++kk) {
                float4 wl = *(const float4*)(&Wl[(k4 * 4 + kk) * 40 + j0]);
                float4 wr = *(const float4*)(&Wr[(k4 * 4 + kk) * 40 + j0]);
#pragma unroll
                for (int i = 0; i < 4; ++i) {
                    float s = ((const float*)&v[i])[kk];
                    accp[i][0] += s * wl.x; accp[i][1] += s * wl.y;
                    accp[i][2] += s * wl.z; accp[i][3] += s * wl.w;
                    accr[i][0] += s * wr.x; accr[i][1] += s * wr.y;
                    accr[i][2] += s * wr.z; accr[i][3] += s * wr.w;
                }
            }
        }
#pragma unroll
        for (int i = 0; i < 4; ++i) {
            int r = r0 + i;
            if (r < N) {
                float4 op, orr;
                op.x = accp[i][0]; op.y = accp[i][1]; op.z = accp[i][2]; op.w = accp[i][3];
                orr.x = accr[i][0]; orr.y = accr[i][1]; orr.z = accr[i][2]; orr.w = accr[i][3];
                *(float4*)(p2 + (size_t)r * D2 + j0) = op;
                *(float4*)(r2 + (size_t)r * D2 + j0) = orr;
            }
        }
    }
}

// ---------------- log_softmax over 40 columns, wave per row ----------------

__global__ void lsm_kernel(const float* __restrict__ h2, float* __restrict__ out, int N) {
    int wid = (blockIdx.x * blockDim.x + threadIdx.x) >> 6;
    int lane = threadIdx.x & 63;
    if (wid >= N) return;
    float v = (lane < D2) ? h2[(size_t)wid * D2 + lane] : -INFINITY;
    float m = v;
    for (int off = 32; off; off >>= 1) m = fmaxf(m, __shfl_xor(m, off));
    float p = (lane < D2) ? expf(v - m) : 0.f;
    float s = p;
    for (int off = 32; off; off >>= 1) s += __shfl_xor(s, off);
    if (lane < D2) out[(size_t)wid * D2 + lane] = v - m - logf(s);
}

// ---------------- launch ----------------

extern "C" void kernel_launch(void* const* d_in, const int* in_sizes, int n_in,
                              void* d_out, int out_size, void* d_ws, size_t ws_size,
                              hipStream_t stream) {
    const float* x   = (const float*)d_in[0];
    const int*   ei  = (const int*)d_in[1];
    const float* W1l = (const float*)d_in[2];
    const float* W1r = (const float*)d_in[3];
    const float* b1  = (const float*)d_in[4];
    const float* W2l = (const float*)d_in[5];
    const float* W2r = (const float*)d_in[6];
    const float* b2  = (const float*)d_in[7];
    float* out = (float*)d_out;

    const int N = N_NODES;
    const int E = in_sizes[1] / 2;
    const int* src = ei;
    const int* dst = ei + E;

    char* p = (char*)d_ws;
    auto alloc = [&](size_t bytes) -> void* {
        void* r = (void*)p;
        p += (bytes + 255) & ~(size_t)255;
        return r;
    };
    int*   deg      = (int*)alloc((size_t)N * 4);
    int*   rowptr   = (int*)alloc((size_t)(N + 1) * 4);
    int*   cursor   = (int*)alloc((size_t)N * 4);
    int*   csr      = (int*)alloc((size_t)E * 4);
    int*   blocksum = (int*)alloc(256 * 4);
    int*   blockoff = (int*)alloc(256 * 4);
    __hip_bfloat16* xh = (__hip_bfloat16*)alloc((size_t)N * D0 * 2);
    float* agg1b    = (float*)alloc((size_t)N * D0 * 4);
    float* hbuf     = (float*)alloc((size_t)N * D1 * 4);
    float* p2buf    = (float*)alloc((size_t)N * D2 * 4);
    float* r2buf    = (float*)alloc((size_t)N * D2 * 4);

    const int nb = (N + 255) / 256;

    hipMemsetAsync(deg, 0, (size_t)N * 4, stream);
    count_deg_kernel<<<(E + 255) / 256, 256, 0, stream>>>(dst, deg, E);
    scanA_kernel<<<nb, 256, 0, stream>>>(deg, blocksum, N);
    scanB_kernel<<<1, 256, 0, stream>>>(blocksum, blockoff, nb, rowptr, N, E);
    scanC_kernel<<<nb, 256, 0, stream>>>(deg, blockoff, rowptr, cursor, N);
    fill_csr_kernel<<<(E + 255) / 256, 256, 0, stream>>>(src, dst, cursor, csr, E);
    cast_x_kernel<<<(N * D0 / 4 + 255) / 256, 256, 0, stream>>>(x, xh, N * D0);

    // layer 1
    agg1_kernel<<<(N * 64 + 255) / 256, 256, 0, stream>>>(xh, rowptr, csr, agg1b, N);
    gemm1_kernel<<<(N + 63) / 64, 256, 0, stream>>>(x, agg1b, W1l, W1r, b1, hbuf, N);

    // layer 2: project first (linearity of mean-aggregation), then gather 40-dim
    gemm2_kernel<<<(N + 127) / 128, 320, 0, stream>>>(hbuf, W2l, W2r, b2, p2buf, r2buf, N);
    agg2_kernel<<<(N * 64 + 255) / 256, 256, 0, stream>>>(p2buf, r2buf, rowptr, csr, out, N);

    // log_softmax into second half of output
    lsm_kernel<<<(N * 64 + 255) / 256, 256, 0, stream>>>(out, out + (size_t)N * D2, N);
}

// Round 5
// 293.303 us; speedup vs baseline: 1.6569x; 1.1978x over previous
//
#include <hip/hip_runtime.h>
#include <hip/hip_bf16.h>
#include <math.h>

#define N_NODES 50000
#define N_EDGES 800000
#define D0 64
#define D1 128
#define D2 40

// ---------------- CSR build ----------------

__global__ void count_deg_kernel(const int* __restrict__ dst, int* __restrict__ deg, int E) {
    int e = blockIdx.x * blockDim.x + threadIdx.x;
    if (e < E) atomicAdd(&deg[dst[e]], 1);
}

__global__ void scanA_kernel(const int* __restrict__ deg, int* __restrict__ blocksum, int N) {
    __shared__ int sd[256];
    int t = threadIdx.x;
    int idx = blockIdx.x * 256 + t;
    int v = (idx < N) ? deg[idx] : 0;
    sd[t] = v;
    __syncthreads();
    for (int off = 128; off; off >>= 1) {
        if (t < off) sd[t] += sd[t + off];
        __syncthreads();
    }
    if (t == 0) blocksum[blockIdx.x] = sd[0];
}

__global__ void scanB_kernel(const int* __restrict__ blocksum, int* __restrict__ blockoff,
                             int nb, int* __restrict__ rowptr, int N, int E) {
    __shared__ int sd[256];
    int t = threadIdx.x;
    int v = (t < nb) ? blocksum[t] : 0;
    sd[t] = v;
    __syncthreads();
    for (int off = 1; off < 256; off <<= 1) {
        int u = (t >= off) ? sd[t - off] : 0;
        __syncthreads();
        sd[t] += u;
        __syncthreads();
    }
    if (t < nb) blockoff[t] = sd[t] - v;
    if (t == 0) rowptr[N] = E;
}

__global__ void scanC_kernel(const int* __restrict__ deg, const int* __restrict__ blockoff,
                             int* __restrict__ rowptr, int* __restrict__ cursor, int N) {
    __shared__ int sd[256];
    int t = threadIdx.x;
    int idx = blockIdx.x * 256 + t;
    int v = (idx < N) ? deg[idx] : 0;
    sd[t] = v;
    __syncthreads();
    for (int off = 1; off < 256; off <<= 1) {
        int u = (t >= off) ? sd[t - off] : 0;
        __syncthreads();
        sd[t] += u;
        __syncthreads();
    }
    if (idx < N) {
        int ex = sd[t] - v + blockoff[blockIdx.x];
        rowptr[idx] = ex;
        cursor[idx] = ex;
    }
}

__global__ void fill_csr_kernel(const int* __restrict__ src, const int* __restrict__ dst,
                                int* __restrict__ cursor, int* __restrict__ csr, int E) {
    int e = blockIdx.x * blockDim.x + threadIdx.x;
    if (e < E) {
        int p = atomicAdd(&cursor[dst[e]], 1);
        csr[p] = src[e];
    }
}

// ---------------- cast x to bf16 (halves agg1 gather bytes) ----------------

__global__ void cast_x_kernel(const float* __restrict__ x, __hip_bfloat16* __restrict__ xh, int n) {
    int i = (blockIdx.x * blockDim.x + threadIdx.x) * 4;
    if (i < n) {
        float4 v = *(const float4*)(x + i);
        xh[i + 0] = __float2bfloat16(v.x);
        xh[i + 1] = __float2bfloat16(v.y);
        xh[i + 2] = __float2bfloat16(v.z);
        xh[i + 3] = __float2bfloat16(v.w);
    }
}

// ---------------- agg1: 8 edges/wave-instr, 8 lanes x 8 bf16 per edge ----------------
// Wave per node. lane = g*8 + l: edge-group g (0..7), feature chunk l (0..7).

__global__ void agg1_kernel(const __hip_bfloat16* __restrict__ xh, const int* __restrict__ rowptr,
                            const int* __restrict__ csr, float* __restrict__ agg, int N) {
    int wid = (blockIdx.x * blockDim.x + threadIdx.x) >> 6;
    int lane = threadIdx.x & 63;
    if (wid >= N) return;
    int beg = rowptr[wid], end = rowptr[wid + 1];
    int deg = end - beg;
    int l = lane & 7, g = lane >> 3;
    float acc[8];
#pragma unroll
    for (int k = 0; k < 8; ++k) acc[k] = 0.f;
    int jmax = (deg + 7) >> 3;   // 8 edges per j
    for (int j = 0; j < jmax; j += 2) {
        int s[2]; float w[2];
#pragma unroll
        for (int u = 0; u < 2; ++u) {
            int slot = (j + u) * 8 + g;
            int e = beg + slot;
            e = (e < end) ? e : (end - 1);       // clamped, unconditional load
            s[u] = csr[e];
            w[u] = (slot < deg) ? 1.f : 0.f;
        }
#pragma unroll
        for (int u = 0; u < 2; ++u) {
            uint4 v = *(const uint4*)((const unsigned short*)xh + (size_t)s[u] * D0 + l * 8);
            float f0 = __uint_as_float(v.x << 16), f1 = __uint_as_float(v.x & 0xffff0000u);
            float f2 = __uint_as_float(v.y << 16), f3 = __uint_as_float(v.y & 0xffff0000u);
            float f4 = __uint_as_float(v.z << 16), f5 = __uint_as_float(v.z & 0xffff0000u);
            float f6 = __uint_as_float(v.w << 16), f7 = __uint_as_float(v.w & 0xffff0000u);
            acc[0] = fmaf(w[u], f0, acc[0]); acc[1] = fmaf(w[u], f1, acc[1]);
            acc[2] = fmaf(w[u], f2, acc[2]); acc[3] = fmaf(w[u], f3, acc[3]);
            acc[4] = fmaf(w[u], f4, acc[4]); acc[5] = fmaf(w[u], f5, acc[5]);
            acc[6] = fmaf(w[u], f6, acc[6]); acc[7] = fmaf(w[u], f7, acc[7]);
        }
    }
    // xor-butterfly over edge-groups (lane bits 3..5); every lane ends with full sum
#pragma unroll
    for (int off = 8; off <= 32; off <<= 1) {
#pragma unroll
        for (int k = 0; k < 8; ++k) acc[k] += __shfl_xor(acc[k], off);
    }
    float inv = 1.f / (float)max(deg, 1);
    if (g == 0) {
        float4 o; o.x = acc[0] * inv; o.y = acc[1] * inv; o.z = acc[2] * inv; o.w = acc[3] * inv;
        *(float4*)(agg + (size_t)wid * D0 + l * 8) = o;
    } else if (g == 1) {
        float4 o; o.x = acc[4] * inv; o.y = acc[5] * inv; o.z = acc[6] * inv; o.w = acc[7] * inv;
        *(float4*)(agg + (size_t)wid * D0 + l * 8 + 4) = o;
    }
}

// ---------------- agg2 + log_softmax (fused): 6 edges/instr, 10 lanes x float4 ----------------
// out[v] = r2[v] + mean p2[src]; out2[v] = log_softmax(out[v])

__global__ void agg2_kernel(const float* __restrict__ p2, const float* __restrict__ r2,
                            const int* __restrict__ rowptr, const int* __restrict__ csr,
                            float* __restrict__ out, float* __restrict__ out2, int N) {
    int wid = (blockIdx.x * blockDim.x + threadIdx.x) >> 6;
    int lane = threadIdx.x & 63;
    if (wid >= N) return;
    int beg = rowptr[wid], end = rowptr[wid + 1];
    int deg = end - beg;
    int g = lane / 10;            // 0..6 (g==6 idle)
    int l = lane - g * 10;        // 0..9
    bool gv = g < 6;
    float ax = 0.f, ay = 0.f, az = 0.f, aw = 0.f;
    int jmax = (deg + 5) / 6;     // 6 edges per j
    for (int j = 0; j < jmax; j += 4) {
        int s[4]; float w[4];
#pragma unroll
        for (int u = 0; u < 4; ++u) {
            int slot = (j + u) * 6 + g;
            int e = beg + slot;
            e = (e < end) ? e : (end - 1);
            s[u] = csr[e];
            w[u] = (gv && slot < deg) ? 1.f : 0.f;
        }
#pragma unroll
        for (int u = 0; u < 4; ++u) {
            float4 v = *(const float4*)(p2 + (size_t)s[u] * D2 + l * 4);
            ax = fmaf(w[u], v.x, ax); ay = fmaf(w[u], v.y, ay);
            az = fmaf(w[u], v.z, az); aw = fmaf(w[u], v.w, aw);
        }
    }
    // reduce over the 6 edge-groups: g0+=g3, g1+=g4, g2+=g5; g0+=g2; g0+=g1
    {
        float bx = __shfl(ax, lane + 30), by = __shfl(ay, lane + 30),
              bz = __shfl(az, lane + 30), bw = __shfl(aw, lane + 30);
        if (g < 3) { ax += bx; ay += by; az += bz; aw += bw; }
        bx = __shfl(ax, lane + 20); by = __shfl(ay, lane + 20);
        bz = __shfl(az, lane + 20); bw = __shfl(aw, lane + 20);
        if (g == 0) { ax += bx; ay += by; az += bz; aw += bw; }
        bx = __shfl(ax, lane + 10); by = __shfl(ay, lane + 10);
        bz = __shfl(az, lane + 10); bw = __shfl(aw, lane + 10);
        if (g == 0) { ax += bx; ay += by; az += bz; aw += bw; }
    }
    float inv = 1.f / (float)max(deg, 1);
    bool wr = (lane < 10);
    float4 h2;
    if (wr) {
        float4 rr = *(const float4*)(r2 + (size_t)wid * D2 + lane * 4);
        h2.x = rr.x + ax * inv; h2.y = rr.y + ay * inv;
        h2.z = rr.z + az * inv; h2.w = rr.w + aw * inv;
        *(float4*)(out + (size_t)wid * D2 + lane * 4) = h2;
    }
    // fused log_softmax over the 40 values held by lanes 0..9
    float m = wr ? fmaxf(fmaxf(h2.x, h2.y), fmaxf(h2.z, h2.w)) : -INFINITY;
#pragma unroll
    for (int off = 1; off < 64; off <<= 1) m = fmaxf(m, __shfl_xor(m, off));
    float s = 0.f;
    if (wr) s = expf(h2.x - m) + expf(h2.y - m) + expf(h2.z - m) + expf(h2.w - m);
#pragma unroll
    for (int off = 1; off < 64; off <<= 1) s += __shfl_xor(s, off);
    if (wr) {
        float lg = m + logf(s);
        float4 o; o.x = h2.x - lg; o.y = h2.y - lg; o.z = h2.z - lg; o.w = h2.w - lg;
        *(float4*)(out2 + (size_t)wid * D2 + lane * 4) = o;
    }
}

// ---------------- GEMM 1: h = relu(x@W1r + agg1@W1l + b1) ----------------
__global__ __launch_bounds__(256) void gemm1_kernel(
        const float* __restrict__ x, const float* __restrict__ agg,
        const float* __restrict__ W1l, const float* __restrict__ W1r,
        const float* __restrict__ b1, float* __restrict__ h, int N) {
    __shared__ float Wc[128 * 128];   // rows 0..63 = W1r (x), 64..127 = W1l (agg)
    int t = threadIdx.x;
    {
        float4* wd = (float4*)Wc;
        const float4* wr = (const float4*)W1r;
        const float4* wl = (const float4*)W1l;
        for (int i = t; i < 4096; i += 256)
            wd[i] = (i < 2048) ? wr[i] : wl[i - 2048];
    }
    __syncthreads();
    int jc = t & 31, j0 = jc * 4;
    int rg = t >> 5;
    float4 bb = *(const float4*)(b1 + j0);
    int ntiles = (N + 63) >> 6;
    for (int tile = blockIdx.x; tile < ntiles; tile += gridDim.x) {
        int r0 = tile * 64 + rg * 8;
        size_t roff[8];
#pragma unroll
        for (int i = 0; i < 8; ++i) {
            int r = r0 + i;
            roff[i] = (size_t)((r < N) ? r : (N - 1)) * D0;
        }
        float acc[8][4];
#pragma unroll
        for (int i = 0; i < 8; ++i) {
            acc[i][0] = bb.x; acc[i][1] = bb.y; acc[i][2] = bb.z; acc[i][3] = bb.w;
        }
#pragma unroll 1
        for (int ph = 0; ph < 2; ++ph) {
            const float* inp = ph ? agg : x;
            const float* wbase = &Wc[(ph * 64) * 128 + j0];
#pragma unroll 2
            for (int k4 = 0; k4 < 16; ++k4) {
                float4 v[8];
#pragma unroll
                for (int i = 0; i < 8; ++i)
                    v[i] = *(const float4*)(inp + roff[i] + k4 * 4);
#pragma unroll
                for (int kk = 0; kk < 4; ++kk) {
                    float4 w = *(const float4*)(wbase + (k4 * 4 + kk) * 128);
#pragma unroll
                    for (int i = 0; i < 8; ++i) {
                        float s = ((const float*)&v[i])[kk];
                        acc[i][0] += s * w.x; acc[i][1] += s * w.y;
                        acc[i][2] += s * w.z; acc[i][3] += s * w.w;
                    }
                }
            }
        }
#pragma unroll
        for (int i = 0; i < 8; ++i) {
            int r = r0 + i;
            if (r < N) {
                float4 o;
                o.x = fmaxf(acc[i][0], 0.f); o.y = fmaxf(acc[i][1], 0.f);
                o.z = fmaxf(acc[i][2], 0.f); o.w = fmaxf(acc[i][3], 0.f);
                *(float4*)(h + (size_t)r * D1 + j0) = o;
            }
        }
    }
}

// ---------------- GEMM 2: p2 = h@W2l, r2 = h@W2r + b2 (one pass over h) ----------------
__global__ __launch_bounds__(320) void gemm2_kernel(
        const float* __restrict__ h,
        const float* __restrict__ W2l, const float* __restrict__ W2r,
        const float* __restrict__ b2,
        float* __restrict__ p2, float* __restrict__ r2, int N) {
    __shared__ float Wl[128 * 40];
    __shared__ float Wr[128 * 40];
    int t = threadIdx.x;
    {
        float4* a = (float4*)Wl;
        float4* b = (float4*)Wr;
        const float4* sa = (const float4*)W2l;
        const float4* sb = (const float4*)W2r;
        for (int i = t; i < 1280; i += 320) { a[i] = sa[i]; b[i] = sb[i]; }
    }
    __syncthreads();
    int jc = t % 10, j0 = jc * 4;
    int rg = t / 10;
    float4 bb = *(const float4*)(b2 + j0);
    int ntiles = (N + 127) >> 7;
    for (int tile = blockIdx.x; tile < ntiles; tile += gridDim.x) {
        int r0 = tile * 128 + rg * 4;
        size_t roff[4];
#pragma unroll
        for (int i = 0; i < 4; ++i) {
            int r = r0 + i;
            roff[i] = (size_t)((r < N) ? r : (N - 1)) * D1;
        }
        float accp[4][4], accr[4][4];
#pragma unroll
        for (int i = 0; i < 4; ++i) {
            accp[i][0] = 0.f; accp[i][1] = 0.f; accp[i][2] = 0.f; accp[i][3] = 0.f;
            accr[i][0] = bb.x; accr[i][1] = bb.y; accr[i][2] = bb.z; accr[i][3] = bb.w;
        }
#pragma unroll 2
        for (int k4 = 0; k4 < 32; ++k4) {
            float4 v[4];
#pragma unroll
            for (int i = 0; i < 4; ++i)
                v[i] = *(const float4*)(h + roff[i] + k4 * 4);
#pragma unroll
            for (int kk = 0; kk < 4; ++kk) {
                float4 wl = *(const float4*)(&Wl[(k4 * 4 + kk) * 40 + j0]);
                float4 wr = *(const float4*)(&Wr[(k4 * 4 + kk) * 40 + j0]);
#pragma unroll
                for (int i = 0; i < 4; ++i) {
                    float s = ((const float*)&v[i])[kk];
                    accp[i][0] += s * wl.x; accp[i][1] += s * wl.y;
                    accp[i][2] += s * wl.z; accp[i][3] += s * wl.w;
                    accr[i][0] += s * wr.x; accr[i][1] += s * wr.y;
                    accr[i][2] += s * wr.z; accr[i][3] += s * wr.w;
                }
            }
        }
#pragma unroll
        for (int i = 0; i < 4; ++i) {
            int r = r0 + i;
            if (r < N) {
                float4 op, orr;
                op.x = accp[i][0]; op.y = accp[i][1]; op.z = accp[i][2]; op.w = accp[i][3];
                orr.x = accr[i][0]; orr.y = accr[i][1]; orr.z = accr[i][2]; orr.w = accr[i][3];
                *(float4*)(p2 + (size_t)r * D2 + j0) = op;
                *(float4*)(r2 + (size_t)r * D2 + j0) = orr;
            }
        }
    }
}

// ---------------- launch ----------------

extern "C" void kernel_launch(void* const* d_in, const int* in_sizes, int n_in,
                              void* d_out, int out_size, void* d_ws, size_t ws_size,
                              hipStream_t stream) {
    const float* x   = (const float*)d_in[0];
    const int*   ei  = (const int*)d_in[1];
    const float* W1l = (const float*)d_in[2];
    const float* W1r = (const float*)d_in[3];
    const float* b1  = (const float*)d_in[4];
    const float* W2l = (const float*)d_in[5];
    const float* W2r = (const float*)d_in[6];
    const float* b2  = (const float*)d_in[7];
    float* out = (float*)d_out;

    const int N = N_NODES;
    const int E = in_sizes[1] / 2;
    const int* src = ei;
    const int* dst = ei + E;

    char* p = (char*)d_ws;
    auto alloc = [&](size_t bytes) -> void* {
        void* r = (void*)p;
        p += (bytes + 255) & ~(size_t)255;
        return r;
    };
    int*   deg      = (int*)alloc((size_t)N * 4);
    int*   rowptr   = (int*)alloc((size_t)(N + 1) * 4);
    int*   cursor   = (int*)alloc((size_t)N * 4);
    int*   csr      = (int*)alloc((size_t)E * 4);
    int*   blocksum = (int*)alloc(256 * 4);
    int*   blockoff = (int*)alloc(256 * 4);
    __hip_bfloat16* xh = (__hip_bfloat16*)alloc((size_t)N * D0 * 2);
    float* agg1b    = (float*)alloc((size_t)N * D0 * 4);
    float* hbuf     = (float*)alloc((size_t)N * D1 * 4);
    float* p2buf    = (float*)alloc((size_t)N * D2 * 4);
    float* r2buf    = (float*)alloc((size_t)N * D2 * 4);

    const int nb = (N + 255) / 256;

    hipMemsetAsync(deg, 0, (size_t)N * 4, stream);
    count_deg_kernel<<<(E + 255) / 256, 256, 0, stream>>>(dst, deg, E);
    scanA_kernel<<<nb, 256, 0, stream>>>(deg, blocksum, N);
    scanB_kernel<<<1, 256, 0, stream>>>(blocksum, blockoff, nb, rowptr, N, E);
    scanC_kernel<<<nb, 256, 0, stream>>>(deg, blockoff, rowptr, cursor, N);
    fill_csr_kernel<<<(E + 255) / 256, 256, 0, stream>>>(src, dst, cursor, csr, E);
    cast_x_kernel<<<(N * D0 / 4 + 255) / 256, 256, 0, stream>>>(x, xh, N * D0);

    // layer 1
    agg1_kernel<<<(N * 64 + 255) / 256, 256, 0, stream>>>(xh, rowptr, csr, agg1b, N);
    gemm1_kernel<<<(N + 63) / 64, 256, 0, stream>>>(x, agg1b, W1l, W1r, b1, hbuf, N);

    // layer 2: project first (linearity), gather 40-dim, fused log_softmax
    gemm2_kernel<<<(N + 127) / 128, 320, 0, stream>>>(hbuf, W2l, W2r, b2, p2buf, r2buf, N);
    agg2_kernel<<<(N * 64 + 255) / 256, 256, 0, stream>>>(p2buf, r2buf, rowptr, csr,
                                                          out, out + (size_t)N * D2, N);
}

// Round 6
// 233.673 us; speedup vs baseline: 2.0798x; 1.2552x over previous
//
#include <hip/hip_runtime.h>
#include <hip/hip_bf16.h>
#include <math.h>

#define N_NODES 50000
#define N_EDGES 800000
#define D0 64
#define D1 128
#define D2 40

#define NB  256   // buckets
#define NPB 196   // nodes per bucket (256*196 = 50176 >= 50000)

// ---------------- bucketed CSR build ----------------
// A: global bucket counts via per-block LDS histogram
__global__ __launch_bounds__(256) void bucket_count_kernel(
        const int* __restrict__ dst, int* __restrict__ bcount, int E) {
    __shared__ int h[NB];
    int t = threadIdx.x;
    h[t] = 0;
    __syncthreads();
    int e0 = blockIdx.x * 2048;
    for (int i = t; i < 2048; i += 256) {
        int e = e0 + i;
        if (e < E) atomicAdd(&h[(unsigned)dst[e] / NPB], 1);
    }
    __syncthreads();
    if (h[t]) atomicAdd(&bcount[t], h[t]);
}

// B: scan bucket counts -> bbase (exclusive), bcursor copy
__global__ void bucket_scan_kernel(const int* __restrict__ bcount,
                                   int* __restrict__ bbase, int* __restrict__ bcursor) {
    __shared__ int sd[NB];
    int t = threadIdx.x;
    int v = bcount[t];
    sd[t] = v;
    __syncthreads();
    for (int off = 1; off < NB; off <<= 1) {
        int u = (t >= off) ? sd[t - off] : 0;
        __syncthreads();
        sd[t] += u;
        __syncthreads();
    }
    int ex = sd[t] - v;
    bbase[t] = ex;
    bcursor[t] = ex;
}

// C: scatter edges into bucket regions as packed (local_dst<<17 | src)
__global__ __launch_bounds__(256) void bucket_scatter_kernel(
        const int* __restrict__ src, const int* __restrict__ dst,
        int* __restrict__ bcursor, unsigned* __restrict__ ebuf, int E) {
    __shared__ int h[NB];
    __shared__ int base[NB];
    int t = threadIdx.x;
    int e0 = blockIdx.x * 4096;
    h[t] = 0;
    __syncthreads();
    for (int i = t; i < 4096; i += 256) {
        int e = e0 + i;
        if (e < E) atomicAdd(&h[(unsigned)dst[e] / NPB], 1);
    }
    __syncthreads();
    if (h[t] > 0) base[t] = atomicAdd(&bcursor[t], h[t]);
    h[t] = 0;   // reuse as local cursor
    __syncthreads();
    for (int i = t; i < 4096; i += 256) {
        int e = e0 + i;
        if (e < E) {
            unsigned d = (unsigned)dst[e];
            unsigned b = d / NPB;
            unsigned ld = d - b * NPB;
            int k = atomicAdd(&h[b], 1);
            ebuf[base[b] + k] = (ld << 17) | (unsigned)src[e];
        }
    }
}

// D: one block per bucket: degree hist + local scan -> rowptr slice; fill csr locally
__global__ __launch_bounds__(256) void bucket_fill_kernel(
        const unsigned* __restrict__ ebuf, const int* __restrict__ bbase,
        int* __restrict__ rowptr, int* __restrict__ csr, int E, int N) {
    __shared__ int cnt[256];
    __shared__ int sd[256];
    int b = blockIdx.x, t = threadIdx.x;
    int s0 = bbase[b];
    int s1 = (b < NB - 1) ? bbase[b + 1] : E;
    int lo = b * NPB;
    cnt[t] = 0;
    __syncthreads();
    for (int i = s0 + t; i < s1; i += 256)
        atomicAdd(&cnt[ebuf[i] >> 17], 1);
    __syncthreads();
    int v = cnt[t];
    sd[t] = v;
    __syncthreads();
    for (int off = 1; off < 256; off <<= 1) {
        int u = (t >= off) ? sd[t - off] : 0;
        __syncthreads();
        sd[t] += u;
        __syncthreads();
    }
    int ex = sd[t] - v;
    int node = lo + t;
    if (t < NPB && node < N) rowptr[node] = s0 + ex;
    cnt[t] = s0 + ex;   // global write cursor (own-index read happened above)
    __syncthreads();
    for (int i = s0 + t; i < s1; i += 256) {
        unsigned pk = ebuf[i];
        int p = atomicAdd(&cnt[pk >> 17], 1);
        csr[p] = (int)(pk & 0x1FFFFu);
    }
    if (b == NB - 1 && t == 0) rowptr[N] = E;
}

// ---------------- cast x to bf16 (halves agg1 gather bytes) ----------------

__global__ void cast_x_kernel(const float* __restrict__ x, __hip_bfloat16* __restrict__ xh, int n) {
    int i = (blockIdx.x * blockDim.x + threadIdx.x) * 4;
    if (i < n) {
        float4 v = *(const float4*)(x + i);
        xh[i + 0] = __float2bfloat16(v.x);
        xh[i + 1] = __float2bfloat16(v.y);
        xh[i + 2] = __float2bfloat16(v.z);
        xh[i + 3] = __float2bfloat16(v.w);
    }
}

// ---------------- agg1: 8 edges/wave-instr, 8 lanes x 8 bf16 per edge ----------------

__global__ void agg1_kernel(const __hip_bfloat16* __restrict__ xh, const int* __restrict__ rowptr,
                            const int* __restrict__ csr, float* __restrict__ agg, int N) {
    int wid = (blockIdx.x * blockDim.x + threadIdx.x) >> 6;
    int lane = threadIdx.x & 63;
    if (wid >= N) return;
    int beg = rowptr[wid], end = rowptr[wid + 1];
    int deg = end - beg;
    int l = lane & 7, g = lane >> 3;
    float acc[8];
#pragma unroll
    for (int k = 0; k < 8; ++k) acc[k] = 0.f;
    int jmax = (deg + 7) >> 3;
    for (int j = 0; j < jmax; j += 2) {
        int s[2]; float w[2];
#pragma unroll
        for (int u = 0; u < 2; ++u) {
            int slot = (j + u) * 8 + g;
            int e = beg + slot;
            e = (e < end) ? e : (end - 1);
            s[u] = csr[e];
            w[u] = (slot < deg) ? 1.f : 0.f;
        }
#pragma unroll
        for (int u = 0; u < 2; ++u) {
            uint4 v = *(const uint4*)((const unsigned short*)xh + (size_t)s[u] * D0 + l * 8);
            float f0 = __uint_as_float(v.x << 16), f1 = __uint_as_float(v.x & 0xffff0000u);
            float f2 = __uint_as_float(v.y << 16), f3 = __uint_as_float(v.y & 0xffff0000u);
            float f4 = __uint_as_float(v.z << 16), f5 = __uint_as_float(v.z & 0xffff0000u);
            float f6 = __uint_as_float(v.w << 16), f7 = __uint_as_float(v.w & 0xffff0000u);
            acc[0] = fmaf(w[u], f0, acc[0]); acc[1] = fmaf(w[u], f1, acc[1]);
            acc[2] = fmaf(w[u], f2, acc[2]); acc[3] = fmaf(w[u], f3, acc[3]);
            acc[4] = fmaf(w[u], f4, acc[4]); acc[5] = fmaf(w[u], f5, acc[5]);
            acc[6] = fmaf(w[u], f6, acc[6]); acc[7] = fmaf(w[u], f7, acc[7]);
        }
    }
#pragma unroll
    for (int off = 8; off <= 32; off <<= 1) {
#pragma unroll
        for (int k = 0; k < 8; ++k) acc[k] += __shfl_xor(acc[k], off);
    }
    float inv = 1.f / (float)max(deg, 1);
    if (g == 0) {
        float4 o; o.x = acc[0] * inv; o.y = acc[1] * inv; o.z = acc[2] * inv; o.w = acc[3] * inv;
        *(float4*)(agg + (size_t)wid * D0 + l * 8) = o;
    } else if (g == 1) {
        float4 o; o.x = acc[4] * inv; o.y = acc[5] * inv; o.z = acc[6] * inv; o.w = acc[7] * inv;
        *(float4*)(agg + (size_t)wid * D0 + l * 8 + 4) = o;
    }
}

// ---------------- agg2 + log_softmax (fused): 6 edges/instr, 10 lanes x float4 ----------------

__global__ void agg2_kernel(const float* __restrict__ p2, const float* __restrict__ r2,
                            const int* __restrict__ rowptr, const int* __restrict__ csr,
                            float* __restrict__ out, float* __restrict__ out2, int N) {
    int wid = (blockIdx.x * blockDim.x + threadIdx.x) >> 6;
    int lane = threadIdx.x & 63;
    if (wid >= N) return;
    int beg = rowptr[wid], end = rowptr[wid + 1];
    int deg = end - beg;
    int g = lane / 10;
    int l = lane - g * 10;
    bool gv = g < 6;
    float ax = 0.f, ay = 0.f, az = 0.f, aw = 0.f;
    int jmax = (deg + 5) / 6;
    for (int j = 0; j < jmax; j += 4) {
        int s[4]; float w[4];
#pragma unroll
        for (int u = 0; u < 4; ++u) {
            int slot = (j + u) * 6 + g;
            int e = beg + slot;
            e = (e < end) ? e : (end - 1);
            s[u] = csr[e];
            w[u] = (gv && slot < deg) ? 1.f : 0.f;
        }
#pragma unroll
        for (int u = 0; u < 4; ++u) {
            float4 v = *(const float4*)(p2 + (size_t)s[u] * D2 + l * 4);
            ax = fmaf(w[u], v.x, ax); ay = fmaf(w[u], v.y, ay);
            az = fmaf(w[u], v.z, az); aw = fmaf(w[u], v.w, aw);
        }
    }
    {
        float bx = __shfl(ax, lane + 30), by = __shfl(ay, lane + 30),
              bz = __shfl(az, lane + 30), bw = __shfl(aw, lane + 30);
        if (g < 3) { ax += bx; ay += by; az += bz; aw += bw; }
        bx = __shfl(ax, lane + 20); by = __shfl(ay, lane + 20);
        bz = __shfl(az, lane + 20); bw = __shfl(aw, lane + 20);
        if (g == 0) { ax += bx; ay += by; az += bz; aw += bw; }
        bx = __shfl(ax, lane + 10); by = __shfl(ay, lane + 10);
        bz = __shfl(az, lane + 10); bw = __shfl(aw, lane + 10);
        if (g == 0) { ax += bx; ay += by; az += bz; aw += bw; }
    }
    float inv = 1.f / (float)max(deg, 1);
    bool wr = (lane < 10);
    float4 h2;
    if (wr) {
        float4 rr = *(const float4*)(r2 + (size_t)wid * D2 + lane * 4);
        h2.x = rr.x + ax * inv; h2.y = rr.y + ay * inv;
        h2.z = rr.z + az * inv; h2.w = rr.w + aw * inv;
        *(float4*)(out + (size_t)wid * D2 + lane * 4) = h2;
    }
    float m = wr ? fmaxf(fmaxf(h2.x, h2.y), fmaxf(h2.z, h2.w)) : -INFINITY;
#pragma unroll
    for (int off = 1; off < 64; off <<= 1) m = fmaxf(m, __shfl_xor(m, off));
    float s = 0.f;
    if (wr) s = expf(h2.x - m) + expf(h2.y - m) + expf(h2.z - m) + expf(h2.w - m);
#pragma unroll
    for (int off = 1; off < 64; off <<= 1) s += __shfl_xor(s, off);
    if (wr) {
        float lg = m + logf(s);
        float4 o; o.x = h2.x - lg; o.y = h2.y - lg; o.z = h2.z - lg; o.w = h2.w - lg;
        *(float4*)(out2 + (size_t)wid * D2 + lane * 4) = o;
    }
}

// ---------------- GEMM 1: h = relu(x@W1r + agg1@W1l + b1) ----------------
__global__ __launch_bounds__(256) void gemm1_kernel(
        const float* __restrict__ x, const float* __restrict__ agg,
        const float* __restrict__ W1l, const float* __restrict__ W1r,
        const float* __restrict__ b1, float* __restrict__ h, int N) {
    __shared__ float Wc[128 * 128];
    int t = threadIdx.x;
    {
        float4* wd = (float4*)Wc;
        const float4* wr = (const float4*)W1r;
        const float4* wl = (const float4*)W1l;
        for (int i = t; i < 4096; i += 256)
            wd[i] = (i < 2048) ? wr[i] : wl[i - 2048];
    }
    __syncthreads();
    int jc = t & 31, j0 = jc * 4;
    int rg = t >> 5;
    float4 bb = *(const float4*)(b1 + j0);
    int ntiles = (N + 63) >> 6;
    for (int tile = blockIdx.x; tile < ntiles; tile += gridDim.x) {
        int r0 = tile * 64 + rg * 8;
        size_t roff[8];
#pragma unroll
        for (int i = 0; i < 8; ++i) {
            int r = r0 + i;
            roff[i] = (size_t)((r < N) ? r : (N - 1)) * D0;
        }
        float acc[8][4];
#pragma unroll
        for (int i = 0; i < 8; ++i) {
            acc[i][0] = bb.x; acc[i][1] = bb.y; acc[i][2] = bb.z; acc[i][3] = bb.w;
        }
#pragma unroll 1
        for (int ph = 0; ph < 2; ++ph) {
            const float* inp = ph ? agg : x;
            const float* wbase = &Wc[(ph * 64) * 128 + j0];
#pragma unroll 2
            for (int k4 = 0; k4 < 16; ++k4) {
                float4 v[8];
#pragma unroll
                for (int i = 0; i < 8; ++i)
                    v[i] = *(const float4*)(inp + roff[i] + k4 * 4);
#pragma unroll
                for (int kk = 0; kk < 4; ++kk) {
                    float4 w = *(const float4*)(wbase + (k4 * 4 + kk) * 128);
#pragma unroll
                    for (int i = 0; i < 8; ++i) {
                        float s = ((const float*)&v[i])[kk];
                        acc[i][0] += s * w.x; acc[i][1] += s * w.y;
                        acc[i][2] += s * w.z; acc[i][3] += s * w.w;
                    }
                }
            }
        }
#pragma unroll
        for (int i = 0; i < 8; ++i) {
            int r = r0 + i;
            if (r < N) {
                float4 o;
                o.x = fmaxf(acc[i][0], 0.f); o.y = fmaxf(acc[i][1], 0.f);
                o.z = fmaxf(acc[i][2], 0.f); o.w = fmaxf(acc[i][3], 0.f);
                *(float4*)(h + (size_t)r * D1 + j0) = o;
            }
        }
    }
}

// ---------------- GEMM 2: p2 = h@W2l, r2 = h@W2r + b2 ----------------
__global__ __launch_bounds__(320) void gemm2_kernel(
        const float* __restrict__ h,
        const float* __restrict__ W2l, const float* __restrict__ W2r,
        const float* __restrict__ b2,
        float* __restrict__ p2, float* __restrict__ r2, int N) {
    __shared__ float Wl[128 * 40];
    __shared__ float Wr[128 * 40];
    int t = threadIdx.x;
    {
        float4* a = (float4*)Wl;
        float4* b = (float4*)Wr;
        const float4* sa = (const float4*)W2l;
        const float4* sb = (const float4*)W2r;
        for (int i = t; i < 1280; i += 320) { a[i] = sa[i]; b[i] = sb[i]; }
    }
    __syncthreads();
    int jc = t % 10, j0 = jc * 4;
    int rg = t / 10;
    float4 bb = *(const float4*)(b2 + j0);
    int ntiles = (N + 127) >> 7;
    for (int tile = blockIdx.x; tile < ntiles; tile += gridDim.x) {
        int r0 = tile * 128 + rg * 4;
        size_t roff[4];
#pragma unroll
        for (int i = 0; i < 4; ++i) {
            int r = r0 + i;
            roff[i] = (size_t)((r < N) ? r : (N - 1)) * D1;
        }
        float accp[4][4], accr[4][4];
#pragma unroll
        for (int i = 0; i < 4; ++i) {
            accp[i][0] = 0.f; accp[i][1] = 0.f; accp[i][2] = 0.f; accp[i][3] = 0.f;
            accr[i][0] = bb.x; accr[i][1] = bb.y; accr[i][2] = bb.z; accr[i][3] = bb.w;
        }
#pragma unroll 2
        for (int k4 = 0; k4 < 32; ++k4) {
            float4 v[4];
#pragma unroll
            for (int i = 0; i < 4; ++i)
                v[i] = *(const float4*)(h + roff[i] + k4 * 4);
#pragma unroll
            for (int kk = 0; kk < 4; ++kk) {
                float4 wl = *(const float4*)(&Wl[(k4 * 4 + kk) * 40 + j0]);
                float4 wr = *(const float4*)(&Wr[(k4 * 4 + kk) * 40 + j0]);
#pragma unroll
                for (int i = 0; i < 4; ++i) {
                    float s = ((const float*)&v[i])[kk];
                    accp[i][0] += s * wl.x; accp[i][1] += s * wl.y;
                    accp[i][2] += s * wl.z; accp[i][3] += s * wl.w;
                    accr[i][0] += s * wr.x; accr[i][1] += s * wr.y;
                    accr[i][2] += s * wr.z; accr[i][3] += s * wr.w;
                }
            }
        }
#pragma unroll
        for (int i = 0; i < 4; ++i) {
            int r = r0 + i;
            if (r < N) {
                float4 op, orr;
                op.x = accp[i][0]; op.y = accp[i][1]; op.z = accp[i][2]; op.w = accp[i][3];
                orr.x = accr[i][0]; orr.y = accr[i][1]; orr.z = accr[i][2]; orr.w = accr[i][3];
                *(float4*)(p2 + (size_t)r * D2 + j0) = op;
                *(float4*)(r2 + (size_t)r * D2 + j0) = orr;
            }
        }
    }
}

// ---------------- launch ----------------

extern "C" void kernel_launch(void* const* d_in, const int* in_sizes, int n_in,
                              void* d_out, int out_size, void* d_ws, size_t ws_size,
                              hipStream_t stream) {
    const float* x   = (const float*)d_in[0];
    const int*   ei  = (const int*)d_in[1];
    const float* W1l = (const float*)d_in[2];
    const float* W1r = (const float*)d_in[3];
    const float* b1  = (const float*)d_in[4];
    const float* W2l = (const float*)d_in[5];
    const float* W2r = (const float*)d_in[6];
    const float* b2  = (const float*)d_in[7];
    float* out = (float*)d_out;

    const int N = N_NODES;
    const int E = in_sizes[1] / 2;
    const int* src = ei;
    const int* dst = ei + E;

    char* p = (char*)d_ws;
    auto alloc = [&](size_t bytes) -> void* {
        void* r = (void*)p;
        p += (bytes + 255) & ~(size_t)255;
        return r;
    };
    int*      rowptr  = (int*)alloc((size_t)(N + 1) * 4);
    int*      csr     = (int*)alloc((size_t)E * 4);
    unsigned* ebuf    = (unsigned*)alloc((size_t)E * 4);
    int*      bcount  = (int*)alloc(NB * 4);
    int*      bbase   = (int*)alloc(NB * 4);
    int*      bcursor = (int*)alloc(NB * 4);
    __hip_bfloat16* xh = (__hip_bfloat16*)alloc((size_t)N * D0 * 2);
    float* agg1b = (float*)alloc((size_t)N * D0 * 4);
    float* hbuf  = (float*)alloc((size_t)N * D1 * 4);
    float* p2buf = (float*)alloc((size_t)N * D2 * 4);
    float* r2buf = (float*)alloc((size_t)N * D2 * 4);

    // bucketed CSR build
    hipMemsetAsync(bcount, 0, NB * 4, stream);
    bucket_count_kernel<<<(E + 2047) / 2048, 256, 0, stream>>>(dst, bcount, E);
    bucket_scan_kernel<<<1, NB, 0, stream>>>(bcount, bbase, bcursor);
    bucket_scatter_kernel<<<(E + 4095) / 4096, 256, 0, stream>>>(src, dst, bcursor, ebuf, E);
    bucket_fill_kernel<<<NB, 256, 0, stream>>>(ebuf, bbase, rowptr, csr, E, N);

    cast_x_kernel<<<(N * D0 / 4 + 255) / 256, 256, 0, stream>>>(x, xh, N * D0);

    // layer 1
    agg1_kernel<<<(N * 64 + 255) / 256, 256, 0, stream>>>(xh, rowptr, csr, agg1b, N);
    gemm1_kernel<<<(N + 63) / 64, 256, 0, stream>>>(x, agg1b, W1l, W1r, b1, hbuf, N);

    // layer 2: project first (linearity), gather 40-dim, fused log_softmax
    gemm2_kernel<<<(N + 127) / 128, 320, 0, stream>>>(hbuf, W2l, W2r, b2, p2buf, r2buf, N);
    agg2_kernel<<<(N * 64 + 255) / 256, 256, 0, stream>>>(p2buf, r2buf, rowptr, csr,
                                                          out, out + (size_t)N * D2, N);
}